// Round 16
// baseline (345.467 us; speedup 1.0000x reference)
//
#include <hip/hip_runtime.h>

// PhysNet interaction block, MI355X (gfx950).
// D=128 features, R=64 radial basis. All matmuls via mfma_f32_16x16x32_bf16.
//
// Internal scratch tensors v and P use a PERMUTED feature layout:
//   feature f = n*16+r  is stored at column  p = r*8+n   (n<8, r<16)
// so MFMA C/D fragments store/load CONTIGUOUS 16-32 B per lane.
//
// ROUND-16: surgical revert of round-15's one regression: g loads back to
// NONTEMPORAL (g is single-touch per pass -- one row per edge, zero reuse --
// so cacheable loads only added L2 allocation pressure: 103->187 us).
// Kept from round 15: WPAD=68 (bank conflicts 2.88M -> 0), 8-elem/thread
// scan, cacheable P stores (P IS reused by edge_gather).
//
// Pipeline:
//   k0 prep_weights : f32 -> bf16 transpose [n][k]; extra blocks zero bins
//   k1 node_pre     : P,v precompute + grid-stride hist(idx_i)
//   k2 scan         : exclusive scan of counts (8 elems/thread)
//   k3 scatter      : perm + sorted sni/snj
//   k4 edge_gather  : G = g[perm]@Wg+bg (MFMA); vp = P[snj]*G (bf16 LDS);
//                     segment-sum over sorted runs -> few atomics
//   k5 phaseB       : 12 fused layers, 64 rows/block, by-value Frag pipeline

#define D 128
#define TILE 64      // node_pre / phaseB tile
#define LDP 136      // padded LDS row length in ushorts
#define SLOT 16384
#define EPB 64       // edges per block in gather
#define WPAD 68      // edge_gather LDS pad (ushorts) -> 0 bank conflicts

typedef __attribute__((ext_vector_type(8))) short s8v;          // 8 x bf16
typedef __attribute__((ext_vector_type(4))) unsigned short us4;
typedef __attribute__((ext_vector_type(4))) float f32x4;
typedef __attribute__((ext_vector_type(4))) int i32x4;

struct Frag { f32x4 v[8]; };       // one wave-slot of a 16x128 C/D tile
struct WReg8 { s8v w[8]; };        // staged weight (16 B/thread x 8, 256 thr)

// fast stable softplus: max(x,0) + ln2*log2(1 + 2^(-|x|*log2e))
__device__ __forceinline__ float sp_act(float x) {
    float t = __builtin_amdgcn_exp2f(-fabsf(x) * 1.44269504088896f);
    return fmaxf(x, 0.f) + 0.69314718055994f * __builtin_amdgcn_logf(1.0f + t);
}
__device__ __forceinline__ unsigned short f2bf(float f) {
    unsigned int u = __float_as_uint(f);
    u += 0x7fffu + ((u >> 16) & 1u);   // round-to-nearest-even
    return (unsigned short)(u >> 16);
}
__device__ __forceinline__ float bf2f(unsigned short h) {
    return __uint_as_float(((unsigned int)h) << 16);
}

// ---------------- k0: weight prep + bin zeroing ----------------
// slots: 0=Wj 1=Wi 2=Wf 3=Wout 4..7=res_int 8..11=res_atom 12..13=res_out 14=Wg
__global__ void prep_weights(
    const float* __restrict__ Wj, const float* __restrict__ Wi,
    const float* __restrict__ Wf, const float* __restrict__ Wout,
    const float* __restrict__ Wri, const float* __restrict__ Wra,
    const float* __restrict__ Wro, const float* __restrict__ Wg,
    unsigned short* __restrict__ wt, int* __restrict__ zbase, int zn)
{
    int id = blockIdx.x;
    if (id >= 15) {                         // zero the bin counters/cursors
        int i = (id - 15) * 256 + threadIdx.x;
        if (i < zn) zbase[i] = 0;
        return;
    }
    const float* src;
    int K = D;
    if      (id == 0)  src = Wj;
    else if (id == 1)  src = Wi;
    else if (id == 2)  src = Wf;
    else if (id == 3)  src = Wout;
    else if (id < 8)   src = Wri + (id - 4) * D * D;
    else if (id < 12)  src = Wra + (id - 8) * D * D;
    else if (id < 14)  src = Wro + (id - 12) * D * D;
    else             { src = Wg; K = 64; }
    unsigned short* dst = wt + id * SLOT;
    int total = K * D;
    for (int e = threadIdx.x; e < total; e += blockDim.x) {
        int k = e >> 7, n = e & 127;       // src row-major [k][n]
        dst[n * K + k] = f2bf(src[e]);     // dst [n][k] (k contiguous)
    }
}

// cooperative load of a 128x128 bf16 transposed weight into padded LDS
__device__ __forceinline__ void load_w128(const unsigned short* __restrict__ wt,
                                          unsigned short (*Wl)[LDP], int t) {
#pragma unroll
    for (int q = 0; q < 8; ++q) {
        int c = t + q * 256;
        int row = c >> 4;
        int k = (c & 15) * 8;
        *(s8v*)&Wl[row][k] = *(const s8v*)(wt + row * 128 + k);
    }
}

// per-wave 16x128 = A(16x128, LDS) * W(128x128, LDS as [n][k]) accumulate
__device__ __forceinline__ void mm128(const unsigned short (*Ax)[LDP],
                                      const unsigned short (*Wl)[LDP],
                                      int wrow, int lane, Frag& acc) {
    int r = lane & 15, g4 = lane >> 4;
#pragma unroll
    for (int k0 = 0; k0 < 4; ++k0) {
        s8v a = *(const s8v*)&Ax[wrow + r][k0 * 32 + g4 * 8];
#pragma unroll
        for (int n = 0; n < 8; ++n) {
            s8v b = *(const s8v*)&Wl[n * 16 + r][k0 * 32 + g4 * 8];
            acc.v[n] = __builtin_amdgcn_mfma_f32_16x16x32_bf16(a, b, acc.v[n], 0, 0, 0);
        }
    }
}

// ---------------- k1: per-node precompute + fused hist ----------------
__global__ __launch_bounds__(256) void node_pre(
    const float* __restrict__ x, const unsigned short* __restrict__ wt,
    const float* __restrict__ bj, const float* __restrict__ bi,
    unsigned short* __restrict__ P, float* __restrict__ v,
    const int* __restrict__ idx_i, int* __restrict__ counts, int E, int N)
{
    __shared__ __align__(16) unsigned short Ax[TILE][LDP];
    __shared__ __align__(16) unsigned short Wl[D][LDP];
    int t = threadIdx.x;
    int r0 = blockIdx.x * TILE;
#pragma unroll
    for (int q = 0; q < 8; ++q) {           // 64x128 f32 tile -> act -> bf16 LDS
        int c = t + q * 256;
        int row = c >> 5;
        int col = (c & 31) * 4;
        int gr = r0 + row;
        f32x4 xv = {0.f, 0.f, 0.f, 0.f};
        if (gr < N) xv = *(const f32x4*)(x + (size_t)gr * D + col);
        us4 w = { f2bf(sp_act(xv[0])), f2bf(sp_act(xv[1])),
                  f2bf(sp_act(xv[2])), f2bf(sp_act(xv[3])) };
        *(us4*)&Ax[row][col] = w;
    }
    load_w128(wt + 0 * SLOT, Wl, t);        // Wj^T
    // prefetch Wi^T into registers (hidden under mm1)
    WReg8 wr;
#pragma unroll
    for (int q = 0; q < 8; ++q) {
        int c = t + q * 256; int row = c >> 4; int k = (c & 15) * 8;
        wr.w[q] = *(const s8v*)(wt + 1 * SLOT + row * 128 + k);
    }
    __syncthreads();

    int lane = t & 63, wv = t >> 6, wrow = wv * 16;
    int r = lane & 15, g4 = lane >> 4;
    Frag acc;
#pragma unroll
    for (int n = 0; n < 8; ++n) { float b = bj[n * 16 + r]; acc.v[n] = (f32x4){b, b, b, b}; }
    mm128(Ax, Wl, wrow, lane, acc);
    // P store, permuted layout: lane writes 8 contiguous bf16 (16 B)
#pragma unroll
    for (int i = 0; i < 4; ++i) {
        int row = r0 + wrow + g4 * 4 + i;
        if (row < N) {
            s8v p;
#pragma unroll
            for (int n = 0; n < 8; ++n) p[n] = (short)f2bf(sp_act(acc.v[n][i]));
            *(s8v*)(P + (size_t)row * D + r * 8) = p;   // P is reused -> cacheable
        }
    }
    __syncthreads();
#pragma unroll
    for (int q = 0; q < 8; ++q) {           // Wi^T from regs
        int c = t + q * 256; int row = c >> 4; int k = (c & 15) * 8;
        *(s8v*)&Wl[row][k] = wr.w[q];
    }
    __syncthreads();
#pragma unroll
    for (int n = 0; n < 8; ++n) { float b = bi[n * 16 + r]; acc.v[n] = (f32x4){b, b, b, b}; }
    mm128(Ax, Wl, wrow, lane, acc);
    // v store, permuted layout: lane writes 8 contiguous f32 (32 B)
#pragma unroll
    for (int i = 0; i < 4; ++i) {
        int row = r0 + wrow + g4 * 4 + i;
        if (row < N) {
            f32x4 lo, hi;
#pragma unroll
            for (int n = 0; n < 4; ++n) {
                lo[n] = sp_act(acc.v[n][i]);
                hi[n] = sp_act(acc.v[n + 4][i]);
            }
            __builtin_nontemporal_store(lo, (f32x4*)(v + (size_t)row * D + r * 8));
            __builtin_nontemporal_store(hi, (f32x4*)(v + (size_t)row * D + r * 8 + 4));
        }
    }
    // fused histogram of idx_i (counts pre-zeroed by prep_weights)
    for (int e = blockIdx.x * blockDim.x + t; e < E; e += gridDim.x * blockDim.x)
        atomicAdd(&counts[idx_i[e]], 1);
}

// ---------------- k2: scan (8 elems/thread, 5 iterations at N=40000) -------
__global__ __launch_bounds__(1024) void scan_kernel(const int* __restrict__ counts,
                                                    int* __restrict__ offsets, int n) {
    __shared__ int wsum[16];
    int t = threadIdx.x, lane = t & 63, w = t >> 6;
    int carry = 0;
    for (int base = 0; base < n; base += 8192) {
        int i0 = base + t * 8;
        int vals[8];
        if (i0 + 7 < n) {
            i32x4 a = *(const i32x4*)(counts + i0);
            i32x4 b = *(const i32x4*)(counts + i0 + 4);
#pragma unroll
            for (int k = 0; k < 4; ++k) { vals[k] = a[k]; vals[k + 4] = b[k]; }
        } else {
#pragma unroll
            for (int k = 0; k < 8; ++k) vals[k] = (i0 + k < n) ? counts[i0 + k] : 0;
        }
        int tsum = 0;
#pragma unroll
        for (int k = 0; k < 8; ++k) tsum += vals[k];
        int s = tsum;                       // inclusive scan over 64 lanes
#pragma unroll
        for (int d = 1; d < 64; d <<= 1) {
            int y = __shfl_up(s, d, 64);
            if (lane >= d) s += y;
        }
        if (lane == 63) wsum[w] = s;
        __syncthreads();
        if (w == 0) {
            int ws = (lane < 16) ? wsum[lane] : 0;
#pragma unroll
            for (int d = 1; d < 16; d <<= 1) {
                int y = __shfl_up(ws, d, 64);
                if (lane >= d) ws += y;
            }
            if (lane < 16) wsum[lane] = ws;
        }
        __syncthreads();
        int wpre = (w == 0) ? 0 : wsum[w - 1];
        int run = carry + wpre + (s - tsum);   // exclusive prefix, 1st elem
#pragma unroll
        for (int k = 0; k < 8; ++k) {
            int i = i0 + k;
            if (i < n) offsets[i] = run;
            run += vals[k];
        }
        int total = wsum[15];
        __syncthreads();
        carry += total;
    }
}
// emits perm + SORTED idx arrays so edge_gather reads everything coalesced
__global__ void scatter_kernel(const int* __restrict__ idx_i,
                               const int* __restrict__ idx_j,
                               const int* __restrict__ offsets,
                               int* __restrict__ cursor, int* __restrict__ perm,
                               int* __restrict__ sni, int* __restrict__ snj, int E) {
    for (int e = blockIdx.x * blockDim.x + threadIdx.x; e < E; e += gridDim.x * blockDim.x) {
        int i = idx_i[e];
        int p = offsets[i] + atomicAdd(&cursor[i], 1);
        perm[p] = e;
        sni[p] = i;
        snj[p] = idx_j[e];
    }
}

// ---------------- k4: edge gather (sorted by idx_i, 256 threads) ----------
__global__ __launch_bounds__(256) void edge_gather(
    const float* __restrict__ g, const int* __restrict__ spe,
    const int* __restrict__ sni, const int* __restrict__ snj,
    const unsigned short* __restrict__ wtg, const float* __restrict__ bg,
    const unsigned short* __restrict__ P, float* __restrict__ v, int E)
{
    // phase A: Gx[64][68] (8704 B) + WG[128][68] (17408 B) = 26112 B
    // phase B: Vx[64][136] bf16 = 17408 B overlays base (barrier-separated)
    __shared__ __align__(16) unsigned char smem[26112];
    __shared__ int s_ni[EPB];
    unsigned short (*Gx)[WPAD] = (unsigned short(*)[WPAD])smem;
    unsigned short (*WG)[WPAD] = (unsigned short(*)[WPAD])(smem + 8704);
    unsigned short (*Vx)[136] = (unsigned short(*)[136])smem;

    int t = threadIdx.x;
    int e0 = blockIdx.x * EPB;
    int lane = t & 63, wv = t >> 6;
    int r = lane & 15, g4 = lane >> 4;

    if (t < EPB) {
        int e = e0 + t;
        s_ni[t] = (e < E) ? sni[e] : -1;       // coalesced
    }

    // ---- g staging: 256B bursts, 16 threads per row; perm lookups hoisted ----
    int pe0, pe1, pe2, pe3;
    {
        int brow = t >> 4;                     // 0..15
        pe0 = (e0 + brow +  0 < E) ? spe[e0 + brow +  0] : -1;
        pe1 = (e0 + brow + 16 < E) ? spe[e0 + brow + 16] : -1;
        pe2 = (e0 + brow + 32 < E) ? spe[e0 + brow + 32] : -1;
        pe3 = (e0 + brow + 48 < E) ? spe[e0 + brow + 48] : -1;
    }
    {
        int col = (t & 15) * 4;                // 0..60 floats
        f32x4 gv0 = {0.f,0.f,0.f,0.f}, gv1 = {0.f,0.f,0.f,0.f};
        f32x4 gv2 = {0.f,0.f,0.f,0.f}, gv3 = {0.f,0.f,0.f,0.f};
        // NONTEMPORAL: g is single-touch (one row per edge) -- round 15 proved
        // cacheable loads here cost +84 us
        if (pe0 >= 0) gv0 = __builtin_nontemporal_load((const f32x4*)(g + (size_t)pe0 * 64 + col));
        if (pe1 >= 0) gv1 = __builtin_nontemporal_load((const f32x4*)(g + (size_t)pe1 * 64 + col));
        if (pe2 >= 0) gv2 = __builtin_nontemporal_load((const f32x4*)(g + (size_t)pe2 * 64 + col));
        if (pe3 >= 0) gv3 = __builtin_nontemporal_load((const f32x4*)(g + (size_t)pe3 * 64 + col));
        int brow = t >> 4;
        us4 w0 = { f2bf(gv0[0]), f2bf(gv0[1]), f2bf(gv0[2]), f2bf(gv0[3]) };
        us4 w1 = { f2bf(gv1[0]), f2bf(gv1[1]), f2bf(gv1[2]), f2bf(gv1[3]) };
        us4 w2 = { f2bf(gv2[0]), f2bf(gv2[1]), f2bf(gv2[2]), f2bf(gv2[3]) };
        us4 w3 = { f2bf(gv3[0]), f2bf(gv3[1]), f2bf(gv3[2]), f2bf(gv3[3]) };
        *(us4*)&Gx[brow +  0][col] = w0;
        *(us4*)&Gx[brow + 16][col] = w1;
        *(us4*)&Gx[brow + 32][col] = w2;
        *(us4*)&Gx[brow + 48][col] = w3;
    }
    // Wg^T -> LDS (128x64 bf16, L2-resident)
#pragma unroll
    for (int q = 0; q < 4; ++q) {
        int c = t + q * 256;
        int row = c >> 3;
        int k = (c & 7) * 8;
        *(s8v*)&WG[row][k] = *(const s8v*)(wtg + row * 64 + k);
    }
    // P fragments prefetched; fly across barrier + MFMA
    s8v pv0, pv1, pv2, pv3;
    {
        int eb = e0 + wv * 16 + g4 * 4;
        int nj0 = (eb + 0 < E) ? snj[eb + 0] : 0;
        int nj1 = (eb + 1 < E) ? snj[eb + 1] : 0;
        int nj2 = (eb + 2 < E) ? snj[eb + 2] : 0;
        int nj3 = (eb + 3 < E) ? snj[eb + 3] : 0;
        pv0 = *(const s8v*)(P + (size_t)nj0 * D + r * 8);
        pv1 = *(const s8v*)(P + (size_t)nj1 * D + r * 8);
        pv2 = *(const s8v*)(P + (size_t)nj2 * D + r * 8);
        pv3 = *(const s8v*)(P + (size_t)nj3 * D + r * 8);
    }
    __syncthreads();

    // ---- G = g@Wg + bg ----
    Frag acc;
#pragma unroll
    for (int n = 0; n < 8; ++n) { float b = bg[n * 16 + r]; acc.v[n] = (f32x4){b, b, b, b}; }
#pragma unroll
    for (int k0 = 0; k0 < 2; ++k0) {
        s8v a = *(const s8v*)&Gx[wv * 16 + r][k0 * 32 + g4 * 8];
#pragma unroll
        for (int n = 0; n < 8; ++n) {
            s8v b = *(const s8v*)&WG[n * 16 + r][k0 * 32 + g4 * 8];
            acc.v[n] = __builtin_amdgcn_mfma_f32_16x16x32_bf16(a, b, acc.v[n], 0, 0, 0);
        }
    }
    __syncthreads();                         // Gx/WG reads done; smem becomes Vx

    // ---- vp = G * P[snj] -> LDS bf16 (permuted layout; 16 B/lane store) ----
#pragma unroll
    for (int i = 0; i < 4; ++i) {
        int el = wv * 16 + g4 * 4 + i;
        bool valid = (e0 + el) < E;
        s8v pvv = (i == 0) ? pv0 : (i == 1) ? pv1 : (i == 2) ? pv2 : pv3;
        s8v outv;
#pragma unroll
        for (int n = 0; n < 8; ++n) {
            float val = valid ? acc.v[n][i] * bf2f((unsigned short)pvv[n]) : 0.f;
            outv[n] = (short)f2bf(val);
        }
        *(s8v*)&Vx[el][r * 8] = outv;
    }
    __syncthreads();

    // ---- segment sum over sorted runs; one atomic per (node-run, feature) ----
    int f = t & 127, half = t >> 7;
    int estart = half * 32;
    int ecap = E - e0; if (ecap > EPB) ecap = EPB;
    int eend = estart + 32; if (eend > ecap) eend = ecap;
    if (estart < eend) {
        float accv = 0.f;
        int cur = s_ni[estart];
        for (int e = estart; e < eend; ++e) {
            int node = s_ni[e];
            if (node != cur) {
                unsafeAtomicAdd(v + (size_t)cur * D + f, accv);
                accv = 0.f; cur = node;
            }
            accv += bf2f(Vx[e][f]);
        }
        unsafeAtomicAdd(v + (size_t)cur * D + f, accv);
    }
}

// ---------------- k5: fused node pipeline (64 rows, 256 threads) -----------
__device__ __forceinline__ void stage_w(WReg8& wr,
                                        const unsigned short* __restrict__ wtp, int t) {
#pragma unroll
    for (int q = 0; q < 8; ++q) {
        int c = t + q * 256; int row = c >> 4; int k = (c & 15) * 8;
        wr.w[q] = *(const s8v*)(wtp + row * 128 + k);
    }
}

// out = act(in)@W + bias [+ resid]; fragments passed/returned BY VALUE so SROA
// keeps them in registers (aliased-pointer version spilled to scratch, round 8).
template <bool RESID>
__device__ __forceinline__ Frag do_layer(
    const Frag in, const Frag resid,
    const float* __restrict__ bias,
    WReg8& wreg, const unsigned short* __restrict__ next_wt,
    unsigned short (*Ax)[LDP], unsigned short (*Wl)[LDP],
    int t, int lane, int wrow, int r, int g4)
{
    __syncthreads();   // previous layer's LDS reads complete
#pragma unroll
    for (int n = 0; n < 8; ++n)
#pragma unroll
        for (int i = 0; i < 4; ++i)
            Ax[wrow + g4 * 4 + i][n * 16 + r] = f2bf(sp_act(in.v[n][i]));
#pragma unroll
    for (int q = 0; q < 8; ++q) {
        int c = t + q * 256; int row = c >> 4; int k = (c & 15) * 8;
        *(s8v*)&Wl[row][k] = wreg.w[q];
    }
    if (next_wt) stage_w(wreg, next_wt, t);   // in flight across barrier + MFMA
    __syncthreads();
    Frag out;
#pragma unroll
    for (int n = 0; n < 8; ++n) {
        float b = bias[n * 16 + r];
        f32x4 bb = {b, b, b, b};
        out.v[n] = RESID ? bb + resid.v[n] : bb;
    }
    mm128(Ax, Wl, wrow, lane, out);
    return out;
}

// natural-layout coalesced tile store via LDS transpose (St aliases Wl)
__device__ __forceinline__ void store_tile(
    const Frag val, float* __restrict__ dst, int r0, int N,
    float (*St)[132], int t, int wv, int r, int g4)
{
    int wrow = wv * 16;
    __syncthreads();
#pragma unroll
    for (int n = 0; n < 8; ++n)
#pragma unroll
        for (int i = 0; i < 4; ++i)
            St[wrow + g4 * 4 + i][n * 16 + r] = val.v[n][i];
    __syncthreads();
#pragma unroll
    for (int q = 0; q < 8; ++q) {
        int idx = t + q * 256;
        int row = idx >> 5, c4 = (idx & 31) * 4;
        int gr = r0 + row;
        if (gr < N) {
            f32x4 vv = *(const f32x4*)&St[row][c4];
            __builtin_nontemporal_store(vv, (f32x4*)(dst + (size_t)gr * D + c4));
        }
    }
}

__global__ __launch_bounds__(256) void phaseB(
    const float* __restrict__ vin, const float* __restrict__ x,
    const float* __restrict__ u, const unsigned short* __restrict__ wt,
    const float* __restrict__ bri, const float* __restrict__ bra,
    const float* __restrict__ bro, const float* __restrict__ bfv,
    const float* __restrict__ bout,
    float* __restrict__ o_out, float* __restrict__ h_out, int N)
{
    __shared__ __align__(16) unsigned short Ax[TILE][LDP];
    __shared__ __align__(16) unsigned short Wl[D][LDP];
    float (*St)[132] = (float(*)[132])Wl;
    int t = threadIdx.x, lane = t & 63, wv = t >> 6, wrow = wv * 16;
    int r = lane & 15, g4 = lane >> 4;
    int r0 = blockIdx.x * TILE;

    WReg8 wreg;
    stage_w(wreg, wt + 4 * SLOT, t);

    Frag h;
#pragma unroll
    for (int i = 0; i < 4; ++i) {            // vin read: permuted -> contiguous
        int row = r0 + wrow + g4 * 4 + i;
        f32x4 lo = {0.f, 0.f, 0.f, 0.f}, hi = {0.f, 0.f, 0.f, 0.f};
        if (row < N) {
            lo = __builtin_nontemporal_load((const f32x4*)(vin + (size_t)row * D + r * 8));
            hi = __builtin_nontemporal_load((const f32x4*)(vin + (size_t)row * D + r * 8 + 4));
        }
#pragma unroll
        for (int n = 0; n < 4; ++n) { h.v[n][i] = lo[n]; h.v[n + 4][i] = hi[n]; }
    }

    Frag t0;
    // residual_stack(v, Wres_int)
    t0 = do_layer<false>(h,  h, bri + 0 * D, wreg, wt +  5 * SLOT, Ax, Wl, t, lane, wrow, r, g4);
    h  = do_layer<true >(t0, h, bri + 1 * D, wreg, wt +  6 * SLOT, Ax, Wl, t, lane, wrow, r, g4);
    t0 = do_layer<false>(h,  h, bri + 2 * D, wreg, wt +  7 * SLOT, Ax, Wl, t, lane, wrow, r, g4);
    h  = do_layer<true >(t0, h, bri + 3 * D, wreg, wt +  2 * SLOT, Ax, Wl, t, lane, wrow, r, g4);
    // ux = u*x  (natural-layout x read; L1-absorbed)
    Frag ux;
#pragma unroll
    for (int n = 0; n < 8; ++n)
#pragma unroll
        for (int i = 0; i < 4; ++i) {
            int row = r0 + wrow + g4 * 4 + i;
            float xv = (row < N) ? x[(size_t)row * D + n * 16 + r] : 0.f;
            ux.v[n][i] = u[n * 16 + r] * xv;
        }
    h  = do_layer<true >(h,  ux, bfv, wreg, wt + 8 * SLOT, Ax, Wl, t, lane, wrow, r, g4);
    // residual_stack(h, Wres_atom)
    t0 = do_layer<false>(h,  h, bra + 0 * D, wreg, wt +  9 * SLOT, Ax, Wl, t, lane, wrow, r, g4);
    h  = do_layer<true >(t0, h, bra + 1 * D, wreg, wt + 10 * SLOT, Ax, Wl, t, lane, wrow, r, g4);
    t0 = do_layer<false>(h,  h, bra + 2 * D, wreg, wt + 11 * SLOT, Ax, Wl, t, lane, wrow, r, g4);
    h  = do_layer<true >(t0, h, bra + 3 * D, wreg, wt + 12 * SLOT, Ax, Wl, t, lane, wrow, r, g4);
    // h output (natural layout, coalesced)
    store_tile(h, h_out, r0, N, St, t, wv, r, g4);
    // residual_stack(h, Wres_out) + final linear
    t0 = do_layer<false>(h,  h, bro + 0 * D, wreg, wt + 13 * SLOT, Ax, Wl, t, lane, wrow, r, g4);
    h  = do_layer<true >(t0, h, bro + 1 * D, wreg, wt +  3 * SLOT, Ax, Wl, t, lane, wrow, r, g4);
    t0 = do_layer<false>(h,  h, bout,        wreg, nullptr,        Ax, Wl, t, lane, wrow, r, g4);
    store_tile(t0, o_out, r0, N, St, t, wv, r, g4);
}

extern "C" void kernel_launch(void* const* d_in, const int* in_sizes, int n_in,
                              void* d_out, int out_size, void* d_ws, size_t ws_size,
                              hipStream_t stream)
{
    const float* x     = (const float*)d_in[0];
    const float* g     = (const float*)d_in[1];
    const int*   idx_i = (const int*)d_in[2];
    const int*   idx_j = (const int*)d_in[3];
    const float* u     = (const float*)d_in[5];
    const float* Wg    = (const float*)d_in[6];
    const float* bg    = (const float*)d_in[7];
    const float* Wj    = (const float*)d_in[8];
    const float* bj    = (const float*)d_in[9];
    const float* Wi    = (const float*)d_in[10];
    const float* bi    = (const float*)d_in[11];
    const float* Wf    = (const float*)d_in[12];
    const float* bf    = (const float*)d_in[13];
    const float* Wri   = (const float*)d_in[14];
    const float* bri   = (const float*)d_in[15];
    const float* Wra   = (const float*)d_in[16];
    const float* bra   = (const float*)d_in[17];
    const float* Wro   = (const float*)d_in[18];
    const float* bro   = (const float*)d_in[19];
    const float* Wout  = (const float*)d_in[20];
    const float* bout  = (const float*)d_in[21];

    int N = in_sizes[0] / D;
    int E = in_sizes[2];

    float* out = (float*)d_out;
    float* v     = out;                                  // f32 scratch -> later o
    float* h_out = out + (size_t)N * D;
    unsigned short* P = (unsigned short*)h_out;          // bf16 scratch -> later h
    unsigned short* wt = (unsigned short*)d_ws;          // 15*16384*2 = 491520 B

    // bin buffers in dead space behind P: 3N + 3E ints = 8.2 MB < 10.2 MB
    int* ibase   = (int*)(out + (size_t)N * D + (size_t)N * D / 2);
    int* counts  = ibase;
    int* offsets = ibase + N;
    int* cursor  = ibase + 2 * (size_t)N;
    int* perm    = ibase + 3 * (size_t)N;
    int* sni     = perm + E;
    int* snj     = sni + E;

    int zn = 3 * N;
    prep_weights<<<15 + (zn + 255) / 256, 256, 0, stream>>>(
        Wj, Wi, Wf, Wout, Wri, Wra, Wro, Wg, wt, ibase, zn);

    int nb = (N + TILE - 1) / TILE;
    node_pre<<<nb, 256, 0, stream>>>(x, wt, bj, bi, P, v, idx_i, counts, E, N);

    scan_kernel<<<1, 1024, 0, stream>>>(counts, offsets, N);
    scatter_kernel<<<1024, 256, 0, stream>>>(idx_i, idx_j, offsets, cursor,
                                             perm, sni, snj, E);

    int eb = (E + EPB - 1) / EPB;
    edge_gather<<<eb, 256, 0, stream>>>(g, perm, sni, snj, wt + 14 * SLOT, bg,
                                        P, v, E);

    phaseB<<<nb, 256, 0, stream>>>(v, x, u, wt, bri, bra, bro, bf, bout,
                                   out, h_out, N);
}

// Round 17
// 345.310 us; speedup vs baseline: 1.0005x; 1.0005x over previous
//
#include <hip/hip_runtime.h>

// PhysNet interaction block, MI355X (gfx950).
// D=128 features, R=64 radial basis. All matmuls via mfma_f32_16x16x32_bf16.
//
// Internal scratch tensors v and P use a PERMUTED feature layout:
//   feature f = n*16+r  is stored at column  p = r*8+n   (n<8, r<16)
// so MFMA C/D fragments store/load CONTIGUOUS 16-32 B per lane.
//
// ROUND-16: surgical revert of round-15's one regression: g loads back to
// NONTEMPORAL (g is single-touch per pass -- one row per edge, zero reuse --
// so cacheable loads only added L2 allocation pressure: 103->187 us).
// Kept from round 15: WPAD=68 (bank conflicts 2.88M -> 0), 8-elem/thread
// scan, cacheable P stores (P IS reused by edge_gather).
//
// Pipeline:
//   k0 prep_weights : f32 -> bf16 transpose [n][k]; extra blocks zero bins
//   k1 node_pre     : P,v precompute + grid-stride hist(idx_i)
//   k2 scan         : exclusive scan of counts (8 elems/thread)
//   k3 scatter      : perm + sorted sni/snj
//   k4 edge_gather  : G = g[perm]@Wg+bg (MFMA); vp = P[snj]*G (bf16 LDS);
//                     segment-sum over sorted runs -> few atomics
//   k5 phaseB       : 12 fused layers, 64 rows/block, by-value Frag pipeline

#define D 128
#define TILE 64      // node_pre / phaseB tile
#define LDP 136      // padded LDS row length in ushorts
#define SLOT 16384
#define EPB 64       // edges per block in gather
#define WPAD 68      // edge_gather LDS pad (ushorts) -> 0 bank conflicts

typedef __attribute__((ext_vector_type(8))) short s8v;          // 8 x bf16
typedef __attribute__((ext_vector_type(4))) unsigned short us4;
typedef __attribute__((ext_vector_type(4))) float f32x4;
typedef __attribute__((ext_vector_type(4))) int i32x4;

struct Frag { f32x4 v[8]; };       // one wave-slot of a 16x128 C/D tile
struct WReg8 { s8v w[8]; };        // staged weight (16 B/thread x 8, 256 thr)

// fast stable softplus: max(x,0) + ln2*log2(1 + 2^(-|x|*log2e))
__device__ __forceinline__ float sp_act(float x) {
    float t = __builtin_amdgcn_exp2f(-fabsf(x) * 1.44269504088896f);
    return fmaxf(x, 0.f) + 0.69314718055994f * __builtin_amdgcn_logf(1.0f + t);
}
__device__ __forceinline__ unsigned short f2bf(float f) {
    unsigned int u = __float_as_uint(f);
    u += 0x7fffu + ((u >> 16) & 1u);   // round-to-nearest-even
    return (unsigned short)(u >> 16);
}
__device__ __forceinline__ float bf2f(unsigned short h) {
    return __uint_as_float(((unsigned int)h) << 16);
}

// ---------------- k0: weight prep + bin zeroing ----------------
// slots: 0=Wj 1=Wi 2=Wf 3=Wout 4..7=res_int 8..11=res_atom 12..13=res_out 14=Wg
__global__ void prep_weights(
    const float* __restrict__ Wj, const float* __restrict__ Wi,
    const float* __restrict__ Wf, const float* __restrict__ Wout,
    const float* __restrict__ Wri, const float* __restrict__ Wra,
    const float* __restrict__ Wro, const float* __restrict__ Wg,
    unsigned short* __restrict__ wt, int* __restrict__ zbase, int zn)
{
    int id = blockIdx.x;
    if (id >= 15) {                         // zero the bin counters/cursors
        int i = (id - 15) * 256 + threadIdx.x;
        if (i < zn) zbase[i] = 0;
        return;
    }
    const float* src;
    int K = D;
    if      (id == 0)  src = Wj;
    else if (id == 1)  src = Wi;
    else if (id == 2)  src = Wf;
    else if (id == 3)  src = Wout;
    else if (id < 8)   src = Wri + (id - 4) * D * D;
    else if (id < 12)  src = Wra + (id - 8) * D * D;
    else if (id < 14)  src = Wro + (id - 12) * D * D;
    else             { src = Wg; K = 64; }
    unsigned short* dst = wt + id * SLOT;
    int total = K * D;
    for (int e = threadIdx.x; e < total; e += blockDim.x) {
        int k = e >> 7, n = e & 127;       // src row-major [k][n]
        dst[n * K + k] = f2bf(src[e]);     // dst [n][k] (k contiguous)
    }
}

// cooperative load of a 128x128 bf16 transposed weight into padded LDS
__device__ __forceinline__ void load_w128(const unsigned short* __restrict__ wt,
                                          unsigned short (*Wl)[LDP], int t) {
#pragma unroll
    for (int q = 0; q < 8; ++q) {
        int c = t + q * 256;
        int row = c >> 4;
        int k = (c & 15) * 8;
        *(s8v*)&Wl[row][k] = *(const s8v*)(wt + row * 128 + k);
    }
}

// per-wave 16x128 = A(16x128, LDS) * W(128x128, LDS as [n][k]) accumulate
__device__ __forceinline__ void mm128(const unsigned short (*Ax)[LDP],
                                      const unsigned short (*Wl)[LDP],
                                      int wrow, int lane, Frag& acc) {
    int r = lane & 15, g4 = lane >> 4;
#pragma unroll
    for (int k0 = 0; k0 < 4; ++k0) {
        s8v a = *(const s8v*)&Ax[wrow + r][k0 * 32 + g4 * 8];
#pragma unroll
        for (int n = 0; n < 8; ++n) {
            s8v b = *(const s8v*)&Wl[n * 16 + r][k0 * 32 + g4 * 8];
            acc.v[n] = __builtin_amdgcn_mfma_f32_16x16x32_bf16(a, b, acc.v[n], 0, 0, 0);
        }
    }
}

// ---------------- k1: per-node precompute + fused hist ----------------
__global__ __launch_bounds__(256) void node_pre(
    const float* __restrict__ x, const unsigned short* __restrict__ wt,
    const float* __restrict__ bj, const float* __restrict__ bi,
    unsigned short* __restrict__ P, float* __restrict__ v,
    const int* __restrict__ idx_i, int* __restrict__ counts, int E, int N)
{
    __shared__ __align__(16) unsigned short Ax[TILE][LDP];
    __shared__ __align__(16) unsigned short Wl[D][LDP];
    int t = threadIdx.x;
    int r0 = blockIdx.x * TILE;
#pragma unroll
    for (int q = 0; q < 8; ++q) {           // 64x128 f32 tile -> act -> bf16 LDS
        int c = t + q * 256;
        int row = c >> 5;
        int col = (c & 31) * 4;
        int gr = r0 + row;
        f32x4 xv = {0.f, 0.f, 0.f, 0.f};
        if (gr < N) xv = *(const f32x4*)(x + (size_t)gr * D + col);
        us4 w = { f2bf(sp_act(xv[0])), f2bf(sp_act(xv[1])),
                  f2bf(sp_act(xv[2])), f2bf(sp_act(xv[3])) };
        *(us4*)&Ax[row][col] = w;
    }
    load_w128(wt + 0 * SLOT, Wl, t);        // Wj^T
    // prefetch Wi^T into registers (hidden under mm1)
    WReg8 wr;
#pragma unroll
    for (int q = 0; q < 8; ++q) {
        int c = t + q * 256; int row = c >> 4; int k = (c & 15) * 8;
        wr.w[q] = *(const s8v*)(wt + 1 * SLOT + row * 128 + k);
    }
    __syncthreads();

    int lane = t & 63, wv = t >> 6, wrow = wv * 16;
    int r = lane & 15, g4 = lane >> 4;
    Frag acc;
#pragma unroll
    for (int n = 0; n < 8; ++n) { float b = bj[n * 16 + r]; acc.v[n] = (f32x4){b, b, b, b}; }
    mm128(Ax, Wl, wrow, lane, acc);
    // P store, permuted layout: lane writes 8 contiguous bf16 (16 B)
#pragma unroll
    for (int i = 0; i < 4; ++i) {
        int row = r0 + wrow + g4 * 4 + i;
        if (row < N) {
            s8v p;
#pragma unroll
            for (int n = 0; n < 8; ++n) p[n] = (short)f2bf(sp_act(acc.v[n][i]));
            *(s8v*)(P + (size_t)row * D + r * 8) = p;   // P is reused -> cacheable
        }
    }
    __syncthreads();
#pragma unroll
    for (int q = 0; q < 8; ++q) {           // Wi^T from regs
        int c = t + q * 256; int row = c >> 4; int k = (c & 15) * 8;
        *(s8v*)&Wl[row][k] = wr.w[q];
    }
    __syncthreads();
#pragma unroll
    for (int n = 0; n < 8; ++n) { float b = bi[n * 16 + r]; acc.v[n] = (f32x4){b, b, b, b}; }
    mm128(Ax, Wl, wrow, lane, acc);
    // v store, permuted layout: lane writes 8 contiguous f32 (32 B)
#pragma unroll
    for (int i = 0; i < 4; ++i) {
        int row = r0 + wrow + g4 * 4 + i;
        if (row < N) {
            f32x4 lo, hi;
#pragma unroll
            for (int n = 0; n < 4; ++n) {
                lo[n] = sp_act(acc.v[n][i]);
                hi[n] = sp_act(acc.v[n + 4][i]);
            }
            __builtin_nontemporal_store(lo, (f32x4*)(v + (size_t)row * D + r * 8));
            __builtin_nontemporal_store(hi, (f32x4*)(v + (size_t)row * D + r * 8 + 4));
        }
    }
    // fused histogram of idx_i (counts pre-zeroed by prep_weights)
    for (int e = blockIdx.x * blockDim.x + t; e < E; e += gridDim.x * blockDim.x)
        atomicAdd(&counts[idx_i[e]], 1);
}

// ---------------- k2: scan (8 elems/thread, 5 iterations at N=40000) -------
__global__ __launch_bounds__(1024) void scan_kernel(const int* __restrict__ counts,
                                                    int* __restrict__ offsets, int n) {
    __shared__ int wsum[16];
    int t = threadIdx.x, lane = t & 63, w = t >> 6;
    int carry = 0;
    for (int base = 0; base < n; base += 8192) {
        int i0 = base + t * 8;
        int vals[8];
        if (i0 + 7 < n) {
            i32x4 a = *(const i32x4*)(counts + i0);
            i32x4 b = *(const i32x4*)(counts + i0 + 4);
#pragma unroll
            for (int k = 0; k < 4; ++k) { vals[k] = a[k]; vals[k + 4] = b[k]; }
        } else {
#pragma unroll
            for (int k = 0; k < 8; ++k) vals[k] = (i0 + k < n) ? counts[i0 + k] : 0;
        }
        int tsum = 0;
#pragma unroll
        for (int k = 0; k < 8; ++k) tsum += vals[k];
        int s = tsum;                       // inclusive scan over 64 lanes
#pragma unroll
        for (int d = 1; d < 64; d <<= 1) {
            int y = __shfl_up(s, d, 64);
            if (lane >= d) s += y;
        }
        if (lane == 63) wsum[w] = s;
        __syncthreads();
        if (w == 0) {
            int ws = (lane < 16) ? wsum[lane] : 0;
#pragma unroll
            for (int d = 1; d < 16; d <<= 1) {
                int y = __shfl_up(ws, d, 64);
                if (lane >= d) ws += y;
            }
            if (lane < 16) wsum[lane] = ws;
        }
        __syncthreads();
        int wpre = (w == 0) ? 0 : wsum[w - 1];
        int run = carry + wpre + (s - tsum);   // exclusive prefix, 1st elem
#pragma unroll
        for (int k = 0; k < 8; ++k) {
            int i = i0 + k;
            if (i < n) offsets[i] = run;
            run += vals[k];
        }
        int total = wsum[15];
        __syncthreads();
        carry += total;
    }
}
// emits perm + SORTED idx arrays so edge_gather reads everything coalesced
__global__ void scatter_kernel(const int* __restrict__ idx_i,
                               const int* __restrict__ idx_j,
                               const int* __restrict__ offsets,
                               int* __restrict__ cursor, int* __restrict__ perm,
                               int* __restrict__ sni, int* __restrict__ snj, int E) {
    for (int e = blockIdx.x * blockDim.x + threadIdx.x; e < E; e += gridDim.x * blockDim.x) {
        int i = idx_i[e];
        int p = offsets[i] + atomicAdd(&cursor[i], 1);
        perm[p] = e;
        sni[p] = i;
        snj[p] = idx_j[e];
    }
}

// ---------------- k4: edge gather (sorted by idx_i, 256 threads) ----------
__global__ __launch_bounds__(256) void edge_gather(
    const float* __restrict__ g, const int* __restrict__ spe,
    const int* __restrict__ sni, const int* __restrict__ snj,
    const unsigned short* __restrict__ wtg, const float* __restrict__ bg,
    const unsigned short* __restrict__ P, float* __restrict__ v, int E)
{
    // phase A: Gx[64][68] (8704 B) + WG[128][68] (17408 B) = 26112 B
    // phase B: Vx[64][136] bf16 = 17408 B overlays base (barrier-separated)
    __shared__ __align__(16) unsigned char smem[26112];
    __shared__ int s_ni[EPB];
    unsigned short (*Gx)[WPAD] = (unsigned short(*)[WPAD])smem;
    unsigned short (*WG)[WPAD] = (unsigned short(*)[WPAD])(smem + 8704);
    unsigned short (*Vx)[136] = (unsigned short(*)[136])smem;

    int t = threadIdx.x;
    int e0 = blockIdx.x * EPB;
    int lane = t & 63, wv = t >> 6;
    int r = lane & 15, g4 = lane >> 4;

    if (t < EPB) {
        int e = e0 + t;
        s_ni[t] = (e < E) ? sni[e] : -1;       // coalesced
    }

    // ---- g staging: 256B bursts, 16 threads per row; perm lookups hoisted ----
    int pe0, pe1, pe2, pe3;
    {
        int brow = t >> 4;                     // 0..15
        pe0 = (e0 + brow +  0 < E) ? spe[e0 + brow +  0] : -1;
        pe1 = (e0 + brow + 16 < E) ? spe[e0 + brow + 16] : -1;
        pe2 = (e0 + brow + 32 < E) ? spe[e0 + brow + 32] : -1;
        pe3 = (e0 + brow + 48 < E) ? spe[e0 + brow + 48] : -1;
    }
    {
        int col = (t & 15) * 4;                // 0..60 floats
        f32x4 gv0 = {0.f,0.f,0.f,0.f}, gv1 = {0.f,0.f,0.f,0.f};
        f32x4 gv2 = {0.f,0.f,0.f,0.f}, gv3 = {0.f,0.f,0.f,0.f};
        // NONTEMPORAL: g is single-touch (one row per edge) -- round 15 proved
        // cacheable loads here cost +84 us
        if (pe0 >= 0) gv0 = __builtin_nontemporal_load((const f32x4*)(g + (size_t)pe0 * 64 + col));
        if (pe1 >= 0) gv1 = __builtin_nontemporal_load((const f32x4*)(g + (size_t)pe1 * 64 + col));
        if (pe2 >= 0) gv2 = __builtin_nontemporal_load((const f32x4*)(g + (size_t)pe2 * 64 + col));
        if (pe3 >= 0) gv3 = __builtin_nontemporal_load((const f32x4*)(g + (size_t)pe3 * 64 + col));
        int brow = t >> 4;
        us4 w0 = { f2bf(gv0[0]), f2bf(gv0[1]), f2bf(gv0[2]), f2bf(gv0[3]) };
        us4 w1 = { f2bf(gv1[0]), f2bf(gv1[1]), f2bf(gv1[2]), f2bf(gv1[3]) };
        us4 w2 = { f2bf(gv2[0]), f2bf(gv2[1]), f2bf(gv2[2]), f2bf(gv2[3]) };
        us4 w3 = { f2bf(gv3[0]), f2bf(gv3[1]), f2bf(gv3[2]), f2bf(gv3[3]) };
        *(us4*)&Gx[brow +  0][col] = w0;
        *(us4*)&Gx[brow + 16][col] = w1;
        *(us4*)&Gx[brow + 32][col] = w2;
        *(us4*)&Gx[brow + 48][col] = w3;
    }
    // Wg^T -> LDS (128x64 bf16, L2-resident)
#pragma unroll
    for (int q = 0; q < 4; ++q) {
        int c = t + q * 256;
        int row = c >> 3;
        int k = (c & 7) * 8;
        *(s8v*)&WG[row][k] = *(const s8v*)(wtg + row * 64 + k);
    }
    // P fragments prefetched; fly across barrier + MFMA
    s8v pv0, pv1, pv2, pv3;
    {
        int eb = e0 + wv * 16 + g4 * 4;
        int nj0 = (eb + 0 < E) ? snj[eb + 0] : 0;
        int nj1 = (eb + 1 < E) ? snj[eb + 1] : 0;
        int nj2 = (eb + 2 < E) ? snj[eb + 2] : 0;
        int nj3 = (eb + 3 < E) ? snj[eb + 3] : 0;
        pv0 = *(const s8v*)(P + (size_t)nj0 * D + r * 8);
        pv1 = *(const s8v*)(P + (size_t)nj1 * D + r * 8);
        pv2 = *(const s8v*)(P + (size_t)nj2 * D + r * 8);
        pv3 = *(const s8v*)(P + (size_t)nj3 * D + r * 8);
    }
    __syncthreads();

    // ---- G = g@Wg + bg ----
    Frag acc;
#pragma unroll
    for (int n = 0; n < 8; ++n) { float b = bg[n * 16 + r]; acc.v[n] = (f32x4){b, b, b, b}; }
#pragma unroll
    for (int k0 = 0; k0 < 2; ++k0) {
        s8v a = *(const s8v*)&Gx[wv * 16 + r][k0 * 32 + g4 * 8];
#pragma unroll
        for (int n = 0; n < 8; ++n) {
            s8v b = *(const s8v*)&WG[n * 16 + r][k0 * 32 + g4 * 8];
            acc.v[n] = __builtin_amdgcn_mfma_f32_16x16x32_bf16(a, b, acc.v[n], 0, 0, 0);
        }
    }
    __syncthreads();                         // Gx/WG reads done; smem becomes Vx

    // ---- vp = G * P[snj] -> LDS bf16 (permuted layout; 16 B/lane store) ----
#pragma unroll
    for (int i = 0; i < 4; ++i) {
        int el = wv * 16 + g4 * 4 + i;
        bool valid = (e0 + el) < E;
        s8v pvv = (i == 0) ? pv0 : (i == 1) ? pv1 : (i == 2) ? pv2 : pv3;
        s8v outv;
#pragma unroll
        for (int n = 0; n < 8; ++n) {
            float val = valid ? acc.v[n][i] * bf2f((unsigned short)pvv[n]) : 0.f;
            outv[n] = (short)f2bf(val);
        }
        *(s8v*)&Vx[el][r * 8] = outv;
    }
    __syncthreads();

    // ---- segment sum over sorted runs; one atomic per (node-run, feature) ----
    int f = t & 127, half = t >> 7;
    int estart = half * 32;
    int ecap = E - e0; if (ecap > EPB) ecap = EPB;
    int eend = estart + 32; if (eend > ecap) eend = ecap;
    if (estart < eend) {
        float accv = 0.f;
        int cur = s_ni[estart];
        for (int e = estart; e < eend; ++e) {
            int node = s_ni[e];
            if (node != cur) {
                unsafeAtomicAdd(v + (size_t)cur * D + f, accv);
                accv = 0.f; cur = node;
            }
            accv += bf2f(Vx[e][f]);
        }
        unsafeAtomicAdd(v + (size_t)cur * D + f, accv);
    }
}

// ---------------- k5: fused node pipeline (64 rows, 256 threads) -----------
__device__ __forceinline__ void stage_w(WReg8& wr,
                                        const unsigned short* __restrict__ wtp, int t) {
#pragma unroll
    for (int q = 0; q < 8; ++q) {
        int c = t + q * 256; int row = c >> 4; int k = (c & 15) * 8;
        wr.w[q] = *(const s8v*)(wtp + row * 128 + k);
    }
}

// out = act(in)@W + bias [+ resid]; fragments passed/returned BY VALUE so SROA
// keeps them in registers (aliased-pointer version spilled to scratch, round 8).
template <bool RESID>
__device__ __forceinline__ Frag do_layer(
    const Frag in, const Frag resid,
    const float* __restrict__ bias,
    WReg8& wreg, const unsigned short* __restrict__ next_wt,
    unsigned short (*Ax)[LDP], unsigned short (*Wl)[LDP],
    int t, int lane, int wrow, int r, int g4)
{
    __syncthreads();   // previous layer's LDS reads complete
#pragma unroll
    for (int n = 0; n < 8; ++n)
#pragma unroll
        for (int i = 0; i < 4; ++i)
            Ax[wrow + g4 * 4 + i][n * 16 + r] = f2bf(sp_act(in.v[n][i]));
#pragma unroll
    for (int q = 0; q < 8; ++q) {
        int c = t + q * 256; int row = c >> 4; int k = (c & 15) * 8;
        *(s8v*)&Wl[row][k] = wreg.w[q];
    }
    if (next_wt) stage_w(wreg, next_wt, t);   // in flight across barrier + MFMA
    __syncthreads();
    Frag out;
#pragma unroll
    for (int n = 0; n < 8; ++n) {
        float b = bias[n * 16 + r];
        f32x4 bb = {b, b, b, b};
        out.v[n] = RESID ? bb + resid.v[n] : bb;
    }
    mm128(Ax, Wl, wrow, lane, out);
    return out;
}

// natural-layout coalesced tile store via LDS transpose (St aliases Wl)
__device__ __forceinline__ void store_tile(
    const Frag val, float* __restrict__ dst, int r0, int N,
    float (*St)[132], int t, int wv, int r, int g4)
{
    int wrow = wv * 16;
    __syncthreads();
#pragma unroll
    for (int n = 0; n < 8; ++n)
#pragma unroll
        for (int i = 0; i < 4; ++i)
            St[wrow + g4 * 4 + i][n * 16 + r] = val.v[n][i];
    __syncthreads();
#pragma unroll
    for (int q = 0; q < 8; ++q) {
        int idx = t + q * 256;
        int row = idx >> 5, c4 = (idx & 31) * 4;
        int gr = r0 + row;
        if (gr < N) {
            f32x4 vv = *(const f32x4*)&St[row][c4];
            __builtin_nontemporal_store(vv, (f32x4*)(dst + (size_t)gr * D + c4));
        }
    }
}

__global__ __launch_bounds__(256) void phaseB(
    const float* __restrict__ vin, const float* __restrict__ x,
    const float* __restrict__ u, const unsigned short* __restrict__ wt,
    const float* __restrict__ bri, const float* __restrict__ bra,
    const float* __restrict__ bro, const float* __restrict__ bfv,
    const float* __restrict__ bout,
    float* __restrict__ o_out, float* __restrict__ h_out, int N)
{
    __shared__ __align__(16) unsigned short Ax[TILE][LDP];
    __shared__ __align__(16) unsigned short Wl[D][LDP];
    float (*St)[132] = (float(*)[132])Wl;
    int t = threadIdx.x, lane = t & 63, wv = t >> 6, wrow = wv * 16;
    int r = lane & 15, g4 = lane >> 4;
    int r0 = blockIdx.x * TILE;

    WReg8 wreg;
    stage_w(wreg, wt + 4 * SLOT, t);

    Frag h;
#pragma unroll
    for (int i = 0; i < 4; ++i) {            // vin read: permuted -> contiguous
        int row = r0 + wrow + g4 * 4 + i;
        f32x4 lo = {0.f, 0.f, 0.f, 0.f}, hi = {0.f, 0.f, 0.f, 0.f};
        if (row < N) {
            lo = __builtin_nontemporal_load((const f32x4*)(vin + (size_t)row * D + r * 8));
            hi = __builtin_nontemporal_load((const f32x4*)(vin + (size_t)row * D + r * 8 + 4));
        }
#pragma unroll
        for (int n = 0; n < 4; ++n) { h.v[n][i] = lo[n]; h.v[n + 4][i] = hi[n]; }
    }

    Frag t0;
    // residual_stack(v, Wres_int)
    t0 = do_layer<false>(h,  h, bri + 0 * D, wreg, wt +  5 * SLOT, Ax, Wl, t, lane, wrow, r, g4);
    h  = do_layer<true >(t0, h, bri + 1 * D, wreg, wt +  6 * SLOT, Ax, Wl, t, lane, wrow, r, g4);
    t0 = do_layer<false>(h,  h, bri + 2 * D, wreg, wt +  7 * SLOT, Ax, Wl, t, lane, wrow, r, g4);
    h  = do_layer<true >(t0, h, bri + 3 * D, wreg, wt +  2 * SLOT, Ax, Wl, t, lane, wrow, r, g4);
    // ux = u*x  (natural-layout x read; L1-absorbed)
    Frag ux;
#pragma unroll
    for (int n = 0; n < 8; ++n)
#pragma unroll
        for (int i = 0; i < 4; ++i) {
            int row = r0 + wrow + g4 * 4 + i;
            float xv = (row < N) ? x[(size_t)row * D + n * 16 + r] : 0.f;
            ux.v[n][i] = u[n * 16 + r] * xv;
        }
    h  = do_layer<true >(h,  ux, bfv, wreg, wt + 8 * SLOT, Ax, Wl, t, lane, wrow, r, g4);
    // residual_stack(h, Wres_atom)
    t0 = do_layer<false>(h,  h, bra + 0 * D, wreg, wt +  9 * SLOT, Ax, Wl, t, lane, wrow, r, g4);
    h  = do_layer<true >(t0, h, bra + 1 * D, wreg, wt + 10 * SLOT, Ax, Wl, t, lane, wrow, r, g4);
    t0 = do_layer<false>(h,  h, bra + 2 * D, wreg, wt + 11 * SLOT, Ax, Wl, t, lane, wrow, r, g4);
    h  = do_layer<true >(t0, h, bra + 3 * D, wreg, wt + 12 * SLOT, Ax, Wl, t, lane, wrow, r, g4);
    // h output (natural layout, coalesced)
    store_tile(h, h_out, r0, N, St, t, wv, r, g4);
    // residual_stack(h, Wres_out) + final linear
    t0 = do_layer<false>(h,  h, bro + 0 * D, wreg, wt + 13 * SLOT, Ax, Wl, t, lane, wrow, r, g4);
    h  = do_layer<true >(t0, h, bro + 1 * D, wreg, wt +  3 * SLOT, Ax, Wl, t, lane, wrow, r, g4);
    t0 = do_layer<false>(h,  h, bout,        wreg, nullptr,        Ax, Wl, t, lane, wrow, r, g4);
    store_tile(t0, o_out, r0, N, St, t, wv, r, g4);
}

extern "C" void kernel_launch(void* const* d_in, const int* in_sizes, int n_in,
                              void* d_out, int out_size, void* d_ws, size_t ws_size,
                              hipStream_t stream)
{
    const float* x     = (const float*)d_in[0];
    const float* g     = (const float*)d_in[1];
    const int*   idx_i = (const int*)d_in[2];
    const int*   idx_j = (const int*)d_in[3];
    const float* u     = (const float*)d_in[5];
    const float* Wg    = (const float*)d_in[6];
    const float* bg    = (const float*)d_in[7];
    const float* Wj    = (const float*)d_in[8];
    const float* bj    = (const float*)d_in[9];
    const float* Wi    = (const float*)d_in[10];
    const float* bi    = (const float*)d_in[11];
    const float* Wf    = (const float*)d_in[12];
    const float* bf    = (const float*)d_in[13];
    const float* Wri   = (const float*)d_in[14];
    const float* bri   = (const float*)d_in[15];
    const float* Wra   = (const float*)d_in[16];
    const float* bra   = (const float*)d_in[17];
    const float* Wro   = (const float*)d_in[18];
    const float* bro   = (const float*)d_in[19];
    const float* Wout  = (const float*)d_in[20];
    const float* bout  = (const float*)d_in[21];

    int N = in_sizes[0] / D;
    int E = in_sizes[2];

    float* out = (float*)d_out;
    float* v     = out;                                  // f32 scratch -> later o
    float* h_out = out + (size_t)N * D;
    unsigned short* P = (unsigned short*)h_out;          // bf16 scratch -> later h
    unsigned short* wt = (unsigned short*)d_ws;          // 15*16384*2 = 491520 B

    // bin buffers in dead space behind P: 3N + 3E ints = 8.2 MB < 10.2 MB
    int* ibase   = (int*)(out + (size_t)N * D + (size_t)N * D / 2);
    int* counts  = ibase;
    int* offsets = ibase + N;
    int* cursor  = ibase + 2 * (size_t)N;
    int* perm    = ibase + 3 * (size_t)N;
    int* sni     = perm + E;
    int* snj     = sni + E;

    int zn = 3 * N;
    prep_weights<<<15 + (zn + 255) / 256, 256, 0, stream>>>(
        Wj, Wi, Wf, Wout, Wri, Wra, Wro, Wg, wt, ibase, zn);

    int nb = (N + TILE - 1) / TILE;
    node_pre<<<nb, 256, 0, stream>>>(x, wt, bj, bi, P, v, idx_i, counts, E, N);

    scan_kernel<<<1, 1024, 0, stream>>>(counts, offsets, N);
    scatter_kernel<<<1024, 256, 0, stream>>>(idx_i, idx_j, offsets, cursor,
                                             perm, sni, snj, E);

    int eb = (E + EPB - 1) / EPB;
    edge_gather<<<eb, 256, 0, stream>>>(g, perm, sni, snj, wt + 14 * SLOT, bg,
                                        P, v, E);

    phaseB<<<nb, 256, 0, stream>>>(v, x, u, wt, bri, bra, bro, bf, bout,
                                   out, h_out, N);
}

// Round 18
// 283.706 us; speedup vs baseline: 1.2177x; 1.2171x over previous
//
#include <hip/hip_runtime.h>

// PhysNet interaction block, MI355X (gfx950).
// D=128 features, R=64 radial basis. All matmuls via mfma_f32_16x16x32_bf16.
//
// Internal scratch tensors v and P use a PERMUTED feature layout:
//   feature f = n*16+r  is stored at column  p = r*8+n   (n<8, r<16)
// so MFMA C/D fragments store/load CONTIGUOUS 16-32 B per lane.
//
// ROUND-18: exact restoration of the round-13 configuration (296 us total,
// edge_gather 103 us) + the proven-safe fast scan. Round 15-17 established:
//  - g loads MUST be nontemporal (single-touch stream): plain cost +84 us.
//  - node_pre's P store MUST be nontemporal: plain P stores left 10 MB dirty
//    across the 8 non-coherent XCD L2s and slowed edge_gather's random P
//    gathers 1.39 -> 0.88 TB/s (+60 us). Producer store policy is part of
//    the consumer's performance contract.
//  - WPAD=72's 2.88M 2-way bank conflicts are free (m136); keep 72.
//
// Pipeline:
//   k0 prep_weights : f32 -> bf16 transpose [n][k]; extra blocks zero bins
//   k1 node_pre     : P,v precompute + grid-stride hist(idx_i)
//   k2 scan         : exclusive scan of counts (8 elems/thread)
//   k3 scatter      : perm + sorted sni/snj
//   k4 edge_gather  : G = g[perm]@Wg+bg (MFMA); vp = P[snj]*G (bf16 LDS);
//                     segment-sum over sorted runs -> few atomics
//   k5 phaseB       : 12 fused layers, 64 rows/block, by-value Frag pipeline

#define D 128
#define TILE 64      // node_pre / phaseB tile
#define LDP 136      // padded LDS row length in ushorts
#define SLOT 16384
#define EPB 64       // edges per block in gather

typedef __attribute__((ext_vector_type(8))) short s8v;          // 8 x bf16
typedef __attribute__((ext_vector_type(4))) unsigned short us4;
typedef __attribute__((ext_vector_type(4))) float f32x4;
typedef __attribute__((ext_vector_type(4))) int i32x4;

struct Frag { f32x4 v[8]; };       // one wave-slot of a 16x128 C/D tile
struct WReg8 { s8v w[8]; };        // staged weight (16 B/thread x 8, 256 thr)

// fast stable softplus: max(x,0) + ln2*log2(1 + 2^(-|x|*log2e))
__device__ __forceinline__ float sp_act(float x) {
    float t = __builtin_amdgcn_exp2f(-fabsf(x) * 1.44269504088896f);
    return fmaxf(x, 0.f) + 0.69314718055994f * __builtin_amdgcn_logf(1.0f + t);
}
__device__ __forceinline__ unsigned short f2bf(float f) {
    unsigned int u = __float_as_uint(f);
    u += 0x7fffu + ((u >> 16) & 1u);   // round-to-nearest-even
    return (unsigned short)(u >> 16);
}
__device__ __forceinline__ float bf2f(unsigned short h) {
    return __uint_as_float(((unsigned int)h) << 16);
}

// ---------------- k0: weight prep + bin zeroing ----------------
// slots: 0=Wj 1=Wi 2=Wf 3=Wout 4..7=res_int 8..11=res_atom 12..13=res_out 14=Wg
__global__ void prep_weights(
    const float* __restrict__ Wj, const float* __restrict__ Wi,
    const float* __restrict__ Wf, const float* __restrict__ Wout,
    const float* __restrict__ Wri, const float* __restrict__ Wra,
    const float* __restrict__ Wro, const float* __restrict__ Wg,
    unsigned short* __restrict__ wt, int* __restrict__ zbase, int zn)
{
    int id = blockIdx.x;
    if (id >= 15) {                         // zero the bin counters/cursors
        int i = (id - 15) * 256 + threadIdx.x;
        if (i < zn) zbase[i] = 0;
        return;
    }
    const float* src;
    int K = D;
    if      (id == 0)  src = Wj;
    else if (id == 1)  src = Wi;
    else if (id == 2)  src = Wf;
    else if (id == 3)  src = Wout;
    else if (id < 8)   src = Wri + (id - 4) * D * D;
    else if (id < 12)  src = Wra + (id - 8) * D * D;
    else if (id < 14)  src = Wro + (id - 12) * D * D;
    else             { src = Wg; K = 64; }
    unsigned short* dst = wt + id * SLOT;
    int total = K * D;
    for (int e = threadIdx.x; e < total; e += blockDim.x) {
        int k = e >> 7, n = e & 127;       // src row-major [k][n]
        dst[n * K + k] = f2bf(src[e]);     // dst [n][k] (k contiguous)
    }
}

// cooperative load of a 128x128 bf16 transposed weight into padded LDS
__device__ __forceinline__ void load_w128(const unsigned short* __restrict__ wt,
                                          unsigned short (*Wl)[LDP], int t) {
#pragma unroll
    for (int q = 0; q < 8; ++q) {
        int c = t + q * 256;
        int row = c >> 4;
        int k = (c & 15) * 8;
        *(s8v*)&Wl[row][k] = *(const s8v*)(wt + row * 128 + k);
    }
}

// per-wave 16x128 = A(16x128, LDS) * W(128x128, LDS as [n][k]) accumulate
__device__ __forceinline__ void mm128(const unsigned short (*Ax)[LDP],
                                      const unsigned short (*Wl)[LDP],
                                      int wrow, int lane, Frag& acc) {
    int r = lane & 15, g4 = lane >> 4;
#pragma unroll
    for (int k0 = 0; k0 < 4; ++k0) {
        s8v a = *(const s8v*)&Ax[wrow + r][k0 * 32 + g4 * 8];
#pragma unroll
        for (int n = 0; n < 8; ++n) {
            s8v b = *(const s8v*)&Wl[n * 16 + r][k0 * 32 + g4 * 8];
            acc.v[n] = __builtin_amdgcn_mfma_f32_16x16x32_bf16(a, b, acc.v[n], 0, 0, 0);
        }
    }
}

// ---------------- k1: per-node precompute + fused hist ----------------
__global__ __launch_bounds__(256) void node_pre(
    const float* __restrict__ x, const unsigned short* __restrict__ wt,
    const float* __restrict__ bj, const float* __restrict__ bi,
    unsigned short* __restrict__ P, float* __restrict__ v,
    const int* __restrict__ idx_i, int* __restrict__ counts, int E, int N)
{
    __shared__ __align__(16) unsigned short Ax[TILE][LDP];
    __shared__ __align__(16) unsigned short Wl[D][LDP];
    int t = threadIdx.x;
    int r0 = blockIdx.x * TILE;
#pragma unroll
    for (int q = 0; q < 8; ++q) {           // 64x128 f32 tile -> act -> bf16 LDS
        int c = t + q * 256;
        int row = c >> 5;
        int col = (c & 31) * 4;
        int gr = r0 + row;
        f32x4 xv = {0.f, 0.f, 0.f, 0.f};
        if (gr < N) xv = *(const f32x4*)(x + (size_t)gr * D + col);
        us4 w = { f2bf(sp_act(xv[0])), f2bf(sp_act(xv[1])),
                  f2bf(sp_act(xv[2])), f2bf(sp_act(xv[3])) };
        *(us4*)&Ax[row][col] = w;
    }
    load_w128(wt + 0 * SLOT, Wl, t);        // Wj^T
    // prefetch Wi^T into registers (hidden under mm1)
    WReg8 wr;
#pragma unroll
    for (int q = 0; q < 8; ++q) {
        int c = t + q * 256; int row = c >> 4; int k = (c & 15) * 8;
        wr.w[q] = *(const s8v*)(wt + 1 * SLOT + row * 128 + k);
    }
    __syncthreads();

    int lane = t & 63, wv = t >> 6, wrow = wv * 16;
    int r = lane & 15, g4 = lane >> 4;
    Frag acc;
#pragma unroll
    for (int n = 0; n < 8; ++n) { float b = bj[n * 16 + r]; acc.v[n] = (f32x4){b, b, b, b}; }
    mm128(Ax, Wl, wrow, lane, acc);
    // P store, permuted layout, NONTEMPORAL (keeps P out of the 8 non-coherent
    // XCD L2s -> edge_gather's random P gathers stay L3-fast; round 15-17)
#pragma unroll
    for (int i = 0; i < 4; ++i) {
        int row = r0 + wrow + g4 * 4 + i;
        if (row < N) {
            s8v p;
#pragma unroll
            for (int n = 0; n < 8; ++n) p[n] = (short)f2bf(sp_act(acc.v[n][i]));
            __builtin_nontemporal_store(p, (s8v*)(P + (size_t)row * D + r * 8));
        }
    }
    __syncthreads();
#pragma unroll
    for (int q = 0; q < 8; ++q) {           // Wi^T from regs
        int c = t + q * 256; int row = c >> 4; int k = (c & 15) * 8;
        *(s8v*)&Wl[row][k] = wr.w[q];
    }
    __syncthreads();
#pragma unroll
    for (int n = 0; n < 8; ++n) { float b = bi[n * 16 + r]; acc.v[n] = (f32x4){b, b, b, b}; }
    mm128(Ax, Wl, wrow, lane, acc);
    // v store, permuted layout: lane writes 8 contiguous f32 (32 B)
#pragma unroll
    for (int i = 0; i < 4; ++i) {
        int row = r0 + wrow + g4 * 4 + i;
        if (row < N) {
            f32x4 lo, hi;
#pragma unroll
            for (int n = 0; n < 4; ++n) {
                lo[n] = sp_act(acc.v[n][i]);
                hi[n] = sp_act(acc.v[n + 4][i]);
            }
            __builtin_nontemporal_store(lo, (f32x4*)(v + (size_t)row * D + r * 8));
            __builtin_nontemporal_store(hi, (f32x4*)(v + (size_t)row * D + r * 8 + 4));
        }
    }
    // fused histogram of idx_i (counts pre-zeroed by prep_weights)
    for (int e = blockIdx.x * blockDim.x + t; e < E; e += gridDim.x * blockDim.x)
        atomicAdd(&counts[idx_i[e]], 1);
}

// ---------------- k2: scan (8 elems/thread, 5 iterations at N=40000) -------
__global__ __launch_bounds__(1024) void scan_kernel(const int* __restrict__ counts,
                                                    int* __restrict__ offsets, int n) {
    __shared__ int wsum[16];
    int t = threadIdx.x, lane = t & 63, w = t >> 6;
    int carry = 0;
    for (int base = 0; base < n; base += 8192) {
        int i0 = base + t * 8;
        int vals[8];
        if (i0 + 7 < n) {
            i32x4 a = *(const i32x4*)(counts + i0);
            i32x4 b = *(const i32x4*)(counts + i0 + 4);
#pragma unroll
            for (int k = 0; k < 4; ++k) { vals[k] = a[k]; vals[k + 4] = b[k]; }
        } else {
#pragma unroll
            for (int k = 0; k < 8; ++k) vals[k] = (i0 + k < n) ? counts[i0 + k] : 0;
        }
        int tsum = 0;
#pragma unroll
        for (int k = 0; k < 8; ++k) tsum += vals[k];
        int s = tsum;                       // inclusive scan over 64 lanes
#pragma unroll
        for (int d = 1; d < 64; d <<= 1) {
            int y = __shfl_up(s, d, 64);
            if (lane >= d) s += y;
        }
        if (lane == 63) wsum[w] = s;
        __syncthreads();
        if (w == 0) {
            int ws = (lane < 16) ? wsum[lane] : 0;
#pragma unroll
            for (int d = 1; d < 16; d <<= 1) {
                int y = __shfl_up(ws, d, 64);
                if (lane >= d) ws += y;
            }
            if (lane < 16) wsum[lane] = ws;
        }
        __syncthreads();
        int wpre = (w == 0) ? 0 : wsum[w - 1];
        int run = carry + wpre + (s - tsum);   // exclusive prefix, 1st elem
#pragma unroll
        for (int k = 0; k < 8; ++k) {
            int i = i0 + k;
            if (i < n) offsets[i] = run;
            run += vals[k];
        }
        int total = wsum[15];
        __syncthreads();
        carry += total;
    }
}
// emits perm + SORTED idx arrays so edge_gather reads everything coalesced
__global__ void scatter_kernel(const int* __restrict__ idx_i,
                               const int* __restrict__ idx_j,
                               const int* __restrict__ offsets,
                               int* __restrict__ cursor, int* __restrict__ perm,
                               int* __restrict__ sni, int* __restrict__ snj, int E) {
    for (int e = blockIdx.x * blockDim.x + threadIdx.x; e < E; e += gridDim.x * blockDim.x) {
        int i = idx_i[e];
        int p = offsets[i] + atomicAdd(&cursor[i], 1);
        perm[p] = e;
        sni[p] = i;
        snj[p] = idx_j[e];
    }
}

// ---------------- k4: edge gather (sorted by idx_i, 256 threads) ----------
__global__ __launch_bounds__(256) void edge_gather(
    const float* __restrict__ g, const int* __restrict__ spe,
    const int* __restrict__ sni, const int* __restrict__ snj,
    const unsigned short* __restrict__ wtg, const float* __restrict__ bg,
    const unsigned short* __restrict__ P, float* __restrict__ v, int E)
{
    // phase A: Gx[64][72] bf16 (9216 B) + WG[128][72] bf16 (18432 B) = 27648 B
    // phase B: Vx[64][136] bf16 = 17408 B overlays base (barrier-separated)
    __shared__ __align__(16) unsigned char smem[27648];
    __shared__ int s_ni[EPB];
    unsigned short (*Gx)[72] = (unsigned short(*)[72])smem;
    unsigned short (*WG)[72] = (unsigned short(*)[72])(smem + 9216);
    unsigned short (*Vx)[136] = (unsigned short(*)[136])smem;

    int t = threadIdx.x;
    int e0 = blockIdx.x * EPB;
    int lane = t & 63, wv = t >> 6;
    int r = lane & 15, g4 = lane >> 4;

    if (t < EPB) {
        int e = e0 + t;
        s_ni[t] = (e < E) ? sni[e] : -1;       // coalesced
    }

    // ---- g staging: 256B bursts, 16 threads per row; perm lookups hoisted ----
    int pe0, pe1, pe2, pe3;
    {
        int brow = t >> 4;                     // 0..15
        pe0 = (e0 + brow +  0 < E) ? spe[e0 + brow +  0] : -1;
        pe1 = (e0 + brow + 16 < E) ? spe[e0 + brow + 16] : -1;
        pe2 = (e0 + brow + 32 < E) ? spe[e0 + brow + 32] : -1;
        pe3 = (e0 + brow + 48 < E) ? spe[e0 + brow + 48] : -1;
    }
    {
        int col = (t & 15) * 4;                // 0..60 floats
        f32x4 gv0 = {0.f,0.f,0.f,0.f}, gv1 = {0.f,0.f,0.f,0.f};
        f32x4 gv2 = {0.f,0.f,0.f,0.f}, gv3 = {0.f,0.f,0.f,0.f};
        // NONTEMPORAL: g is single-touch (one row per edge); round 15 measured
        // cacheable loads here at +84 us
        if (pe0 >= 0) gv0 = __builtin_nontemporal_load((const f32x4*)(g + (size_t)pe0 * 64 + col));
        if (pe1 >= 0) gv1 = __builtin_nontemporal_load((const f32x4*)(g + (size_t)pe1 * 64 + col));
        if (pe2 >= 0) gv2 = __builtin_nontemporal_load((const f32x4*)(g + (size_t)pe2 * 64 + col));
        if (pe3 >= 0) gv3 = __builtin_nontemporal_load((const f32x4*)(g + (size_t)pe3 * 64 + col));
        int brow = t >> 4;
        us4 w0 = { f2bf(gv0[0]), f2bf(gv0[1]), f2bf(gv0[2]), f2bf(gv0[3]) };
        us4 w1 = { f2bf(gv1[0]), f2bf(gv1[1]), f2bf(gv1[2]), f2bf(gv1[3]) };
        us4 w2 = { f2bf(gv2[0]), f2bf(gv2[1]), f2bf(gv2[2]), f2bf(gv2[3]) };
        us4 w3 = { f2bf(gv3[0]), f2bf(gv3[1]), f2bf(gv3[2]), f2bf(gv3[3]) };
        *(us4*)&Gx[brow +  0][col] = w0;
        *(us4*)&Gx[brow + 16][col] = w1;
        *(us4*)&Gx[brow + 32][col] = w2;
        *(us4*)&Gx[brow + 48][col] = w3;
    }
    // Wg^T -> LDS (128x64 bf16, L2-resident)
#pragma unroll
    for (int q = 0; q < 4; ++q) {
        int c = t + q * 256;
        int row = c >> 3;
        int k = (c & 7) * 8;
        *(s8v*)&WG[row][k] = *(const s8v*)(wtg + row * 64 + k);
    }
    // P fragments prefetched; fly across barrier + MFMA
    s8v pv0, pv1, pv2, pv3;
    {
        int eb = e0 + wv * 16 + g4 * 4;
        int nj0 = (eb + 0 < E) ? snj[eb + 0] : 0;
        int nj1 = (eb + 1 < E) ? snj[eb + 1] : 0;
        int nj2 = (eb + 2 < E) ? snj[eb + 2] : 0;
        int nj3 = (eb + 3 < E) ? snj[eb + 3] : 0;
        pv0 = *(const s8v*)(P + (size_t)nj0 * D + r * 8);
        pv1 = *(const s8v*)(P + (size_t)nj1 * D + r * 8);
        pv2 = *(const s8v*)(P + (size_t)nj2 * D + r * 8);
        pv3 = *(const s8v*)(P + (size_t)nj3 * D + r * 8);
    }
    __syncthreads();

    // ---- G = g@Wg + bg ----
    Frag acc;
#pragma unroll
    for (int n = 0; n < 8; ++n) { float b = bg[n * 16 + r]; acc.v[n] = (f32x4){b, b, b, b}; }
#pragma unroll
    for (int k0 = 0; k0 < 2; ++k0) {
        s8v a = *(const s8v*)&Gx[wv * 16 + r][k0 * 32 + g4 * 8];
#pragma unroll
        for (int n = 0; n < 8; ++n) {
            s8v b = *(const s8v*)&WG[n * 16 + r][k0 * 32 + g4 * 8];
            acc.v[n] = __builtin_amdgcn_mfma_f32_16x16x32_bf16(a, b, acc.v[n], 0, 0, 0);
        }
    }
    __syncthreads();                         // Gx/WG reads done; smem becomes Vx

    // ---- vp = G * P[snj] -> LDS bf16 (permuted layout; 16 B/lane store) ----
#pragma unroll
    for (int i = 0; i < 4; ++i) {
        int el = wv * 16 + g4 * 4 + i;
        bool valid = (e0 + el) < E;
        s8v pvv = (i == 0) ? pv0 : (i == 1) ? pv1 : (i == 2) ? pv2 : pv3;
        s8v outv;
#pragma unroll
        for (int n = 0; n < 8; ++n) {
            float val = valid ? acc.v[n][i] * bf2f((unsigned short)pvv[n]) : 0.f;
            outv[n] = (short)f2bf(val);
        }
        *(s8v*)&Vx[el][r * 8] = outv;
    }
    __syncthreads();

    // ---- segment sum over sorted runs; one atomic per (node-run, feature) ----
    int f = t & 127, half = t >> 7;
    int estart = half * 32;
    int ecap = E - e0; if (ecap > EPB) ecap = EPB;
    int eend = estart + 32; if (eend > ecap) eend = ecap;
    if (estart < eend) {
        float accv = 0.f;
        int cur = s_ni[estart];
        for (int e = estart; e < eend; ++e) {
            int node = s_ni[e];
            if (node != cur) {
                unsafeAtomicAdd(v + (size_t)cur * D + f, accv);
                accv = 0.f; cur = node;
            }
            accv += bf2f(Vx[e][f]);
        }
        unsafeAtomicAdd(v + (size_t)cur * D + f, accv);
    }
}

// ---------------- k5: fused node pipeline (64 rows, 256 threads) -----------
__device__ __forceinline__ void stage_w(WReg8& wr,
                                        const unsigned short* __restrict__ wtp, int t) {
#pragma unroll
    for (int q = 0; q < 8; ++q) {
        int c = t + q * 256; int row = c >> 4; int k = (c & 15) * 8;
        wr.w[q] = *(const s8v*)(wtp + row * 128 + k);
    }
}

// out = act(in)@W + bias [+ resid]; fragments passed/returned BY VALUE so SROA
// keeps them in registers (aliased-pointer version spilled to scratch, round 8).
template <bool RESID>
__device__ __forceinline__ Frag do_layer(
    const Frag in, const Frag resid,
    const float* __restrict__ bias,
    WReg8& wreg, const unsigned short* __restrict__ next_wt,
    unsigned short (*Ax)[LDP], unsigned short (*Wl)[LDP],
    int t, int lane, int wrow, int r, int g4)
{
    __syncthreads();   // previous layer's LDS reads complete
#pragma unroll
    for (int n = 0; n < 8; ++n)
#pragma unroll
        for (int i = 0; i < 4; ++i)
            Ax[wrow + g4 * 4 + i][n * 16 + r] = f2bf(sp_act(in.v[n][i]));
#pragma unroll
    for (int q = 0; q < 8; ++q) {
        int c = t + q * 256; int row = c >> 4; int k = (c & 15) * 8;
        *(s8v*)&Wl[row][k] = wreg.w[q];
    }
    if (next_wt) stage_w(wreg, next_wt, t);   // in flight across barrier + MFMA
    __syncthreads();
    Frag out;
#pragma unroll
    for (int n = 0; n < 8; ++n) {
        float b = bias[n * 16 + r];
        f32x4 bb = {b, b, b, b};
        out.v[n] = RESID ? bb + resid.v[n] : bb;
    }
    mm128(Ax, Wl, wrow, lane, out);
    return out;
}

// natural-layout coalesced tile store via LDS transpose (St aliases Wl)
__device__ __forceinline__ void store_tile(
    const Frag val, float* __restrict__ dst, int r0, int N,
    float (*St)[132], int t, int wv, int r, int g4)
{
    int wrow = wv * 16;
    __syncthreads();
#pragma unroll
    for (int n = 0; n < 8; ++n)
#pragma unroll
        for (int i = 0; i < 4; ++i)
            St[wrow + g4 * 4 + i][n * 16 + r] = val.v[n][i];
    __syncthreads();
#pragma unroll
    for (int q = 0; q < 8; ++q) {
        int idx = t + q * 256;
        int row = idx >> 5, c4 = (idx & 31) * 4;
        int gr = r0 + row;
        if (gr < N) {
            f32x4 vv = *(const f32x4*)&St[row][c4];
            __builtin_nontemporal_store(vv, (f32x4*)(dst + (size_t)gr * D + c4));
        }
    }
}

__global__ __launch_bounds__(256) void phaseB(
    const float* __restrict__ vin, const float* __restrict__ x,
    const float* __restrict__ u, const unsigned short* __restrict__ wt,
    const float* __restrict__ bri, const float* __restrict__ bra,
    const float* __restrict__ bro, const float* __restrict__ bfv,
    const float* __restrict__ bout,
    float* __restrict__ o_out, float* __restrict__ h_out, int N)
{
    __shared__ __align__(16) unsigned short Ax[TILE][LDP];
    __shared__ __align__(16) unsigned short Wl[D][LDP];
    float (*St)[132] = (float(*)[132])Wl;
    int t = threadIdx.x, lane = t & 63, wv = t >> 6, wrow = wv * 16;
    int r = lane & 15, g4 = lane >> 4;
    int r0 = blockIdx.x * TILE;

    WReg8 wreg;
    stage_w(wreg, wt + 4 * SLOT, t);

    Frag h;
#pragma unroll
    for (int i = 0; i < 4; ++i) {            // vin read: permuted -> contiguous
        int row = r0 + wrow + g4 * 4 + i;
        f32x4 lo = {0.f, 0.f, 0.f, 0.f}, hi = {0.f, 0.f, 0.f, 0.f};
        if (row < N) {
            lo = __builtin_nontemporal_load((const f32x4*)(vin + (size_t)row * D + r * 8));
            hi = __builtin_nontemporal_load((const f32x4*)(vin + (size_t)row * D + r * 8 + 4));
        }
#pragma unroll
        for (int n = 0; n < 4; ++n) { h.v[n][i] = lo[n]; h.v[n + 4][i] = hi[n]; }
    }

    Frag t0;
    // residual_stack(v, Wres_int)
    t0 = do_layer<false>(h,  h, bri + 0 * D, wreg, wt +  5 * SLOT, Ax, Wl, t, lane, wrow, r, g4);
    h  = do_layer<true >(t0, h, bri + 1 * D, wreg, wt +  6 * SLOT, Ax, Wl, t, lane, wrow, r, g4);
    t0 = do_layer<false>(h,  h, bri + 2 * D, wreg, wt +  7 * SLOT, Ax, Wl, t, lane, wrow, r, g4);
    h  = do_layer<true >(t0, h, bri + 3 * D, wreg, wt +  2 * SLOT, Ax, Wl, t, lane, wrow, r, g4);
    // ux = u*x  (natural-layout x read; L1-absorbed)
    Frag ux;
#pragma unroll
    for (int n = 0; n < 8; ++n)
#pragma unroll
        for (int i = 0; i < 4; ++i) {
            int row = r0 + wrow + g4 * 4 + i;
            float xv = (row < N) ? x[(size_t)row * D + n * 16 + r] : 0.f;
            ux.v[n][i] = u[n * 16 + r] * xv;
        }
    h  = do_layer<true >(h,  ux, bfv, wreg, wt + 8 * SLOT, Ax, Wl, t, lane, wrow, r, g4);
    // residual_stack(h, Wres_atom)
    t0 = do_layer<false>(h,  h, bra + 0 * D, wreg, wt +  9 * SLOT, Ax, Wl, t, lane, wrow, r, g4);
    h  = do_layer<true >(t0, h, bra + 1 * D, wreg, wt + 10 * SLOT, Ax, Wl, t, lane, wrow, r, g4);
    t0 = do_layer<false>(h,  h, bra + 2 * D, wreg, wt + 11 * SLOT, Ax, Wl, t, lane, wrow, r, g4);
    h  = do_layer<true >(t0, h, bra + 3 * D, wreg, wt + 12 * SLOT, Ax, Wl, t, lane, wrow, r, g4);
    // h output (natural layout, coalesced)
    store_tile(h, h_out, r0, N, St, t, wv, r, g4);
    // residual_stack(h, Wres_out) + final linear
    t0 = do_layer<false>(h,  h, bro + 0 * D, wreg, wt + 13 * SLOT, Ax, Wl, t, lane, wrow, r, g4);
    h  = do_layer<true >(t0, h, bro + 1 * D, wreg, wt +  3 * SLOT, Ax, Wl, t, lane, wrow, r, g4);
    t0 = do_layer<false>(h,  h, bout,        wreg, nullptr,        Ax, Wl, t, lane, wrow, r, g4);
    store_tile(t0, o_out, r0, N, St, t, wv, r, g4);
}

extern "C" void kernel_launch(void* const* d_in, const int* in_sizes, int n_in,
                              void* d_out, int out_size, void* d_ws, size_t ws_size,
                              hipStream_t stream)
{
    const float* x     = (const float*)d_in[0];
    const float* g     = (const float*)d_in[1];
    const int*   idx_i = (const int*)d_in[2];
    const int*   idx_j = (const int*)d_in[3];
    const float* u     = (const float*)d_in[5];
    const float* Wg    = (const float*)d_in[6];
    const float* bg    = (const float*)d_in[7];
    const float* Wj    = (const float*)d_in[8];
    const float* bj    = (const float*)d_in[9];
    const float* Wi    = (const float*)d_in[10];
    const float* bi    = (const float*)d_in[11];
    const float* Wf    = (const float*)d_in[12];
    const float* bf    = (const float*)d_in[13];
    const float* Wri   = (const float*)d_in[14];
    const float* bri   = (const float*)d_in[15];
    const float* Wra   = (const float*)d_in[16];
    const float* bra   = (const float*)d_in[17];
    const float* Wro   = (const float*)d_in[18];
    const float* bro   = (const float*)d_in[19];
    const float* Wout  = (const float*)d_in[20];
    const float* bout  = (const float*)d_in[21];

    int N = in_sizes[0] / D;
    int E = in_sizes[2];

    float* out = (float*)d_out;
    float* v     = out;                                  // f32 scratch -> later o
    float* h_out = out + (size_t)N * D;
    unsigned short* P = (unsigned short*)h_out;          // bf16 scratch -> later h
    unsigned short* wt = (unsigned short*)d_ws;          // 15*16384*2 = 491520 B

    // bin buffers in dead space behind P: 3N + 3E ints = 8.2 MB < 10.2 MB
    int* ibase   = (int*)(out + (size_t)N * D + (size_t)N * D / 2);
    int* counts  = ibase;
    int* offsets = ibase + N;
    int* cursor  = ibase + 2 * (size_t)N;
    int* perm    = ibase + 3 * (size_t)N;
    int* sni     = perm + E;
    int* snj     = sni + E;

    int zn = 3 * N;
    prep_weights<<<15 + (zn + 255) / 256, 256, 0, stream>>>(
        Wj, Wi, Wf, Wout, Wri, Wra, Wro, Wg, wt, ibase, zn);

    int nb = (N + TILE - 1) / TILE;
    node_pre<<<nb, 256, 0, stream>>>(x, wt, bj, bi, P, v, idx_i, counts, E, N);

    scan_kernel<<<1, 1024, 0, stream>>>(counts, offsets, N);
    scatter_kernel<<<1024, 256, 0, stream>>>(idx_i, idx_j, offsets, cursor,
                                             perm, sni, snj, E);

    int eb = (E + EPB - 1) / EPB;
    edge_gather<<<eb, 256, 0, stream>>>(g, perm, sni, snj, wt + 14 * SLOT, bg,
                                        P, v, E);

    phaseB<<<nb, 256, 0, stream>>>(v, x, u, wt, bri, bra, bro, bf, bout,
                                   out, h_out, N);
}